// Round 9
// baseline (427.822 us; speedup 1.0000x reference)
//
#include <hip/hip_runtime.h>

// Problem constants (from reference)
#define B_  16
#define T_  2048
#define IN_ 512
#define H_  512
#define M_  (B_ * T_)

// R18: fusion round 3. R16 proved the flag protocol CORRECT (absmax 0.0) but
// died on regalloc: launch_bounds(256,3) only sets MIN waves/EU, the
// occupancy heuristic over-achieved (VGPR 84, 6 waves/EU) and spilled acc ->
// ~1GB scratch (WRITE 998MB). Fixes here:
//   1. amdgpu_waves_per_eu(2,3): max=3 removes the incentive to allocate
//      below ~170 VGPR; GEMM path needs 116 -> no spill expected.
//   2. #pragma unroll 1 on the 2-tile persistence loop (single tile body).
//   3. BK=16 tile (R17: BK=32 was 216us, conflicts 0 but slower -> revert).
// Geometry (validated R13): 512 producers x 2 tiles (t-major phases) run at
// full per-tile speed at 2 blocks/CU; 32 consumer blocks co-resident consume
// 128-t chunks via device-scope flags. 544 blocks <= 3/CU capacity.
// Producers never wait on consumers -> worst case is serialization, not hang.
#define BM 128
#define BN 128
#define BK 16
#define LDT (BM + 4)

#define NGEMM 512   // gemm blocks, 2 tiles each = 1024 tiles
#define NSCAN 32    // scan blocks x 256 threads = 8192 chains

// Tile-ready flags, one producer each; two consumer waves -> two copies, each
// consumed-and-RESET by exactly one wave => self-cleaning across graph
// replays (device globals zero-init at load; kernel exits all-zero).
// Protocol hardware-validated in R16 (passed, absmax 0.0).
__device__ unsigned g_flagA[1024];
__device__ unsigned g_flagB[1024];

static __device__ __forceinline__ float4 ld4(const float* p) {
    return *reinterpret_cast<const float4*>(p);
}

// ---------------------------------------------------------------------------
// One GEMM tile: h[m0:+128][n0:+128]. Body verbatim from the validated
// kernel (absmax 0.0 across R2-R17). k accumulated strictly in order 0..511
// with fmaf. DO NOT reorder the k loop.
// ---------------------------------------------------------------------------
__device__ __forceinline__
void gemm_tile(const float* __restrict__ X, const float* __restrict__ W,
               const float* __restrict__ bias, float* __restrict__ Hout,
               int m0, int n0, int tid,
               float (*As)[LDT], float (*Bs)[LDT]) {
    const int tx = tid & 15;           // col group
    const int ty = tid >> 4;           // row group

    const int row = tid >> 2;          // 0..63
    const int kph = (tid & 3) * 4;     // 0,4,8,12

    const float* pa0 = X + (size_t)(m0 + row) * IN_ + kph;
    const float* pa1 = pa0 + (size_t)64 * IN_;
    const float* pb0 = W + (size_t)(n0 + row) * IN_ + kph;
    const float* pb1 = pb0 + (size_t)64 * IN_;

    float4 ra0 = ld4(pa0), ra1 = ld4(pa1), rb0 = ld4(pb0), rb1 = ld4(pb1);

    float acc[8][8];
#pragma unroll
    for (int i = 0; i < 8; ++i)
#pragma unroll
        for (int j = 0; j < 8; ++j) acc[i][j] = 0.0f;

    for (int k0 = 0; k0 < IN_; k0 += BK) {
        As[kph + 0][row]      = ra0.x;  As[kph + 1][row]      = ra0.y;
        As[kph + 2][row]      = ra0.z;  As[kph + 3][row]      = ra0.w;
        As[kph + 0][row + 64] = ra1.x;  As[kph + 1][row + 64] = ra1.y;
        As[kph + 2][row + 64] = ra1.z;  As[kph + 3][row + 64] = ra1.w;
        Bs[kph + 0][row]      = rb0.x;  Bs[kph + 1][row]      = rb0.y;
        Bs[kph + 2][row]      = rb0.z;  Bs[kph + 3][row]      = rb0.w;
        Bs[kph + 0][row + 64] = rb1.x;  Bs[kph + 1][row + 64] = rb1.y;
        Bs[kph + 2][row + 64] = rb1.z;  Bs[kph + 3][row + 64] = rb1.w;
        __syncthreads();

        // prefetch next k-tile into registers; drains during the 16-k compute
        if (k0 + BK < IN_) {
            ra0 = ld4(pa0 + k0 + BK);  ra1 = ld4(pa1 + k0 + BK);
            rb0 = ld4(pb0 + k0 + BK);  rb1 = ld4(pb1 + k0 + BK);
        }

#pragma unroll
        for (int k = 0; k < BK; ++k) {
            float4 av0 = ld4(&As[k][ty * 4]);
            float4 av1 = ld4(&As[k][ty * 4 + 64]);
            float4 bv0 = ld4(&Bs[k][tx * 4]);
            float4 bv1 = ld4(&Bs[k][tx * 4 + 64]);
            const float am[8] = {av0.x, av0.y, av0.z, av0.w,
                                 av1.x, av1.y, av1.z, av1.w};
            const float bn8[8] = {bv0.x, bv0.y, bv0.z, bv0.w,
                                  bv1.x, bv1.y, bv1.z, bv1.w};
#pragma unroll
            for (int i = 0; i < 8; ++i)
#pragma unroll
                for (int j = 0; j < 8; ++j)
                    acc[i][j] = fmaf(am[i], bn8[j], acc[i][j]);
        }
        __syncthreads();
    }

    // epilogue: + bias (bias is zeros -> exact), coalesced float4 stores
    float4 bb0 = ld4(&bias[n0 + tx * 4]);
    float4 bb1 = ld4(&bias[n0 + tx * 4 + 64]);
#pragma unroll
    for (int i = 0; i < 8; ++i) {
        const int r2 = m0 + ((i < 4) ? (ty * 4 + i) : (64 + ty * 4 + (i - 4)));
        float4 o0, o1;
        o0.x = acc[i][0] + bb0.x;  o0.y = acc[i][1] + bb0.y;
        o0.z = acc[i][2] + bb0.z;  o0.w = acc[i][3] + bb0.w;
        o1.x = acc[i][4] + bb1.x;  o1.y = acc[i][5] + bb1.y;
        o1.z = acc[i][6] + bb1.z;  o1.w = acc[i][7] + bb1.w;
        *reinterpret_cast<float4*>(&Hout[(size_t)r2 * H_ + n0 + tx * 4])      = o0;
        *reinterpret_cast<float4*>(&Hout[(size_t)r2 * H_ + n0 + tx * 4 + 64]) = o1;
    }
}

// ---------------------------------------------------------------------------
// Scan step batch (16 steps). Arithmetic statements byte-identical to the
// validated R10-R17 step (absmax 0.0). DO NOT touch.
// ---------------------------------------------------------------------------
__device__ __forceinline__
void scan_compute16(const float* __restrict__ buf, float* __restrict__ sarr,
                    float& v, float& theta) {
    const float DECAY_F = 0.9048374180359595f;  // exp(-1/10)
    const float ALPHA_F = 0.01f;
#pragma unroll
    for (int j = 0; j < 16; ++j) {
        float cur = buf[j];
        v = v * DECAY_F + cur;
        float cl = 32.0f * theta;                  // L * theta * 2
        v = __builtin_amdgcn_fmed3f(v, -cl, cl);   // == fminf(fmaxf(v,-cl),cl)

        // ---- v/theta: raw rcp seed + Markstein correction (validated) ----
        float r0 = __builtin_amdgcn_rcpf(theta);   // ~1 ulp seed
        float q0 = v * r0;
        float er = fmaf(-theta, q0, v);            // exact residual
        float q  = fmaf(er, r0, q0);               // RN quotient to O(ulp^2)
        // ------------------------------------------------------------------

        float s = floorf(q);
        s = __builtin_amdgcn_fmed3f(s, 0.0f, 16.0f); // == fminf(fmaxf(s,0),16)
        v = v - s * theta;
        theta = theta + ALPHA_F * s - ALPHA_F * (theta - 1.0f);
        sarr[j] = s;                               // register array
    }
}

// ---------------------------------------------------------------------------
// Fused kernel. Blocks 0..511: persistent GEMM (2 tiles, t-major phases,
// publish flag per tile). Blocks 512..543: scan consumers (4 waves each, one
// 64-chain wave per flag; no __syncthreads in this path).
// amdgpu_waves_per_eu(2,3): min 2 (VGPR cap 256), max 3 (no incentive to
// allocate below ~170) -> GEMM path (116) must not spill. 544 blocks fit
// 3/CU capacity -> co-resident -> overlap.
// ---------------------------------------------------------------------------
__global__
__attribute__((amdgpu_flat_work_group_size(256, 256), amdgpu_waves_per_eu(2, 3)))
void fused_gemm_scan(const float* __restrict__ X, const float* __restrict__ W,
                     const float* __restrict__ bias, float* __restrict__ Hbuf,
                     float* __restrict__ spikes, float* __restrict__ vout,
                     float* __restrict__ thout) {
    __shared__ float As[BK][LDT];
    __shared__ float Bs[BK][LDT];

    if (blockIdx.x < NGEMM) {
        // ---------------- producer: 2 GEMM tiles, t-major ----------------
        const int tid = threadIdx.x;
        const int g   = blockIdx.x;        // 0..511
        const int tt7 = g >> 6;            // 0..7  (t-octile -> early t first)
        const int bb  = (g >> 2) & 15;     // batch
        const int nt  = g & 3;             // n-tile
#pragma unroll 1
        for (int ph = 0; ph < 2; ++ph) {
            const int tt = tt7 + ph * 8;   // 0..15
            const int mt = bb * 16 + tt;   // m-tile = (b, t-chunk)
            gemm_tile(X, W, bias, Hbuf, mt * BM, nt * BN, tid, As, Bs);
            __syncthreads();               // wave convergence before publish
            if (tid == 0) {
                const int tau = mt * 4 + nt;
                __hip_atomic_store(&g_flagA[tau], 1u, __ATOMIC_RELEASE,
                                   __HIP_MEMORY_SCOPE_AGENT);
                __hip_atomic_store(&g_flagB[tau], 1u, __ATOMIC_RELEASE,
                                   __HIP_MEMORY_SCOPE_AGENT);
            }
        }
    } else {
        // ---------------- consumer: GIF scan, flag-gated chunks ----------
        const int s   = blockIdx.x - NGEMM;
        const int gid = s * 256 + (int)threadIdx.x;   // 0..8191
        const int b   = gid >> 9;
        const int h   = gid & 511;

        const float* ip = Hbuf   + (size_t)b * T_ * H_ + h;
        float*       sp = spikes + (size_t)b * T_ * H_ + h;

        // wave-uniform flag selection: h>>6 parity picks the copy,
        // h>>7 picks the n-tile. (64-lane wave spans one 64-aligned h range.)
        unsigned* flagbase = ((h >> 6) & 1) ? g_flagB : g_flagA;
        const int ntq = h >> 7;

        float bufA[16], bufB[16], sA[16], sB[16];
        float v = 0.0f, theta = 1.0f;

        for (int c = 0; c < 16; ++c) {            // 16 chunks of 128 t
            const int t0 = c * 128;
            unsigned* fp = flagbase + ((size_t)(b * 16 + c) * 4 + ntq);
            while (__hip_atomic_load(fp, __ATOMIC_ACQUIRE,
                                     __HIP_MEMORY_SCOPE_AGENT) == 0u)
                __builtin_amdgcn_s_sleep(8);
            // consume-and-reset (self-cleaning for the next graph replay)
            __hip_atomic_store(fp, 0u, __ATOMIC_RELAXED,
                               __HIP_MEMORY_SCOPE_AGENT);

            // 8 batches of 16 steps, double-buffered (R11 pattern, validated)
#pragma unroll
            for (int j = 0; j < 16; ++j) bufA[j] = ip[(size_t)(t0 + j) * H_];
            for (int bt = 0; bt < 8; bt += 2) {
#pragma unroll
                for (int j = 0; j < 16; ++j)
                    bufB[j] = ip[(size_t)(t0 + (bt + 1) * 16 + j) * H_];
                asm volatile("" ::: "memory");
                scan_compute16(bufA, sA, v, theta);
#pragma unroll
                for (int j = 0; j < 16; ++j)
                    sp[(size_t)(t0 + bt * 16 + j) * H_] = sA[j];

                if (bt + 2 < 8) {
#pragma unroll
                    for (int j = 0; j < 16; ++j)
                        bufA[j] = ip[(size_t)(t0 + (bt + 2) * 16 + j) * H_];
                }
                asm volatile("" ::: "memory");
                scan_compute16(bufB, sB, v, theta);
#pragma unroll
                for (int j = 0; j < 16; ++j)
                    sp[(size_t)(t0 + (bt + 1) * 16 + j) * H_] = sB[j];
            }
        }
        vout[gid]  = v;
        thout[gid] = theta;
    }
}

// ---------------------------------------------------------------------------
extern "C" void kernel_launch(void* const* d_in, const int* in_sizes, int n_in,
                              void* d_out, int out_size, void* d_ws, size_t ws_size,
                              hipStream_t stream) {
    const float* x    = (const float*)d_in[0];   // [16, 2048, 512]
    const float* W    = (const float*)d_in[1];   // [512, 512]
    const float* bias = (const float*)d_in[2];   // [512]

    float* out    = (float*)d_out;
    float* spikes = out;
    float* v_f    = out + (size_t)M_ * H_;
    float* th_f   = v_f + (size_t)B_ * H_;

    float* hbuf   = (float*)d_ws;                // 64 MiB scratch for h

    fused_gemm_scan<<<NGEMM + NSCAN, 256, 0, stream>>>(
        x, W, bias, hbuf, spikes, v_f, th_f);
}